// Round 8
// baseline (63.780 us; speedup 1.0000x reference)
//
#include <hip/hip_runtime.h>
#include <math.h>

// YOLO loss on MI355X. prediction (N,7,7,30) f32, target (N,7,7,25) f32.
// R7 = R6's proven dual-path double-buffered pipeline (pred via
// global_load_lds DMA, tgt via float4->VGPR->ds_write) + FUSED finalize:
// blocks atomicAdd partials into 16 line-spread slots, release-increment a
// ticket; the last-ticket block acquire-loads slots and writes out[0..5].
// Graph = {memset 2052 B, yolo_partial} — the second kernel dispatch is gone.
constexpr int TOT    = 16384 * 7 * 7;        // 802816 cells
constexpr int TILE   = 64;                   // cells per tile
constexpr int NTILES = TOT / TILE;           // 12544
constexpr int NBLK   = 1280;                 // 5 blocks/CU x 256 CU, resident
constexpr int NSLOT  = 16;                   // line-spread atomic slots
constexpr int SLOT_STRIDE = 32;              // floats (128 B) per slot
constexpr float INV_N = 1.0f / 16384.0f;
constexpr float INV7  = 1.0f / 7.0f;

constexpr int PRED_TILE_B = TILE * 30 * 4;   // 7680 B (480 float4)
constexpr int TGT_TILE_B  = TILE * 25 * 4;   // 6400 B (400 float4)
constexpr int BUF_B       = 14336;           // per-tile LDS buffer

__device__ __forceinline__ float fast_rcp(float x) {
    return __builtin_amdgcn_rcpf(x);         // v_rcp_f32, ~1ulp
}

// DMA 16 B per active lane: global (per-lane addr) -> LDS (wave base + lane*16)
__device__ __forceinline__ void dma16(const void* g, void* lds) {
    __builtin_amdgcn_global_load_lds(
        (const __attribute__((address_space(1))) void*)g,
        (__attribute__((address_space(3))) void*)lds, 16, 0, 0);
}

__global__ __launch_bounds__(64) void yolo_partial(
    const float* __restrict__ pred, const float* __restrict__ tgt,
    float* __restrict__ acc /* NSLOT*SLOT_STRIDE f32 + uint ticket, zeroed */,
    float* __restrict__ out)
{
    __shared__ float4 smem4[2 * BUF_B / 16];     // 28672 B
    char* smem = (char*)smem4;

    const int l   = threadIdx.x;                 // 0..63, one wave
    const int bid = blockIdx.x;

    float a_xy = 0.0f, a_wh = 0.0f, a_co = 0.0f, a_cn = 0.0f, a_cl = 0.0f;

    const int nt = (NTILES - bid + NBLK - 1) / NBLK;   // 9 or 10 tiles

    float4 tr0, tr1, tr2, tr3, tr4, tr5, tr6;    // tgt staging regs (28 VGPR)

#define LD_TGT(tile_)                                                       \
    {                                                                       \
        const float4* gt4 = reinterpret_cast<const float4*>(               \
            tgt + (long)(tile_) * (TILE * 25));                             \
        tr0 = gt4[l];        tr1 = gt4[l + 64];  tr2 = gt4[l + 128];        \
        tr3 = gt4[l + 192];  tr4 = gt4[l + 256]; tr5 = gt4[l + 320];        \
        if (l < 16) tr6 = gt4[l + 384];                                     \
    }  /* 7 vmcnt ops */

#define DMA_PRED(tile_, b)                                                  \
    {                                                                       \
        const char* gp = (const char*)pred + (long)(tile_) * PRED_TILE_B;   \
        char* lb = smem + (b) * BUF_B;                                      \
        _Pragma("unroll")                                                   \
        for (int i = 0; i < 7; ++i)                                         \
            dma16(gp + (size_t)(l + i * 64) * 16, lb + i * 1024);           \
        if (l < 32) dma16(gp + (size_t)(l + 448) * 16, lb + 7168);          \
    }  /* 8 vmcnt ops */

#define ST_TGT(b)                                                           \
    {                                                                       \
        float4* st4 = reinterpret_cast<float4*>(smem + (b) * BUF_B + 7680); \
        st4[l]       = tr0;  st4[l + 64]  = tr1;  st4[l + 128] = tr2;       \
        st4[l + 192] = tr3;  st4[l + 256] = tr4;  st4[l + 320] = tr5;       \
        if (l < 16) st4[l + 384] = tr6;                                     \
    }

    // prologue: stage tile 0 into buf 0
    LD_TGT(bid);
    DMA_PRED(bid, 0);
    asm volatile("s_waitcnt vmcnt(8)" ::: "memory");   // tgt loads retired
    __builtin_amdgcn_sched_barrier(0);
    ST_TGT(0);
    int buf = 0;

    for (int k = 0; k < nt; ++k) {
        const int tile = bid + k * NBLK;
        if (k + 1 < nt) {
            LD_TGT(bid + (k + 1) * NBLK);             // 7 loads
            DMA_PRED(bid + (k + 1) * NBLK, buf ^ 1);  // 8 DMA
            asm volatile("s_waitcnt vmcnt(15)" ::: "memory");  // pred(k) landed
        } else {
            asm volatile("s_waitcnt vmcnt(0)" ::: "memory");
        }
        __builtin_amdgcn_sched_barrier(0);

        // ---- compute tile k from LDS buf ----
        const float* pred_s = (const float*)(smem + buf * BUF_B);
        const float* tgt_s  = pred_s + TILE * 30;

        const int   cell = tile * TILE + l;
        const int   col  = cell % 7;
        const int   row  = (cell / 7) % 7;
        const float fcol = (float)col, frow = (float)row;

        float pv[30];
        {
            const float2* p2 = reinterpret_cast<const float2*>(pred_s + l * 30);
#pragma unroll
            for (int i = 0; i < 15; ++i) {
                float2 v = p2[i];
                pv[2 * i] = v.x; pv[2 * i + 1] = v.y;
            }
        }
        float tv[25];
        {
            const float* tp = tgt_s + l * 25;   // stride 25: conflict-free b32
#pragma unroll
            for (int kk = 0; kk < 25; ++kk) tv[kk] = tp[kk];
        }

        const float conf  = tv[4];
        const bool  noobj = (conf == 0.0f);

        // target abs corners, scaled by conf (reference: _rel2abs(target)*conf)
        float xc = (tv[0] + fcol) * INV7, yc = (tv[1] + frow) * INV7;
        float hw = tv[2] * 0.5f,          hh = tv[3] * 0.5f;
        float tx1 = (xc - hw) * conf, ty1 = (yc - hh) * conf;
        float tx2 = (xc + hw) * conf, ty2 = (yc + hh) * conf;
        float t_area = (tx2 - tx1) * (ty2 - ty1);

        // pred box 1
        float xc1 = (pv[0] + fcol) * INV7, yc1 = (pv[1] + frow) * INV7;
        float hw1 = pv[2] * 0.5f,          hh1 = pv[3] * 0.5f;
        float bx1 = xc1 - hw1, by1 = yc1 - hh1, bx2 = xc1 + hw1, by2 = yc1 + hh1;
        float xi1 = fmaxf(tx1, bx1), yi1 = fmaxf(ty1, by1);
        float xi2 = fminf(tx2, bx2), yi2 = fminf(ty2, by2);
        float inter1 = fmaxf(xi2 - xi1, 0.0f) * fmaxf(yi2 - yi1, 0.0f);
        float area1  = (bx2 - bx1) * (by2 - by1);
        float iou1 = inter1 * fast_rcp(t_area + area1 - inter1 + 1e-6f);

        // pred box 2
        float xc2 = (pv[5] + fcol) * INV7, yc2 = (pv[6] + frow) * INV7;
        float hw2 = pv[7] * 0.5f,          hh2 = pv[8] * 0.5f;
        float cx1 = xc2 - hw2, cy1 = yc2 - hh2, cx2 = xc2 + hw2, cy2 = yc2 + hh2;
        float xj1 = fmaxf(tx1, cx1), yj1 = fmaxf(ty1, cy1);
        float xj2 = fminf(tx2, cx2), yj2 = fminf(ty2, cy2);
        float inter2 = fmaxf(xj2 - xj1, 0.0f) * fmaxf(yj2 - yj1, 0.0f);
        float area2  = (cx2 - cx1) * (cy2 - cy1);
        float iou2 = inter2 * fast_rcp(t_area + area2 - inter2 + 1e-6f);

        // NB: reference as written picks box2 when iou1 > iou2
        const bool pick2 = iou1 > iou2;
        float hx  = pick2 ? pv[5] : pv[0];
        float hy  = pick2 ? pv[6] : pv[1];
        float hwv = pick2 ? pv[7] : pv[2];
        float hhv = pick2 ? pv[8] : pv[3];
        float hc  = pick2 ? pv[9] : pv[4];

        // loss_xy
        float px = noobj ? 0.0f : fmaxf(hx, 0.0f);
        float py = noobj ? 0.0f : fmaxf(hy, 0.0f);
        float dx = tv[0] - px, dy = tv[1] - py;
        a_xy += dx * dx + dy * dy;
        // loss_wh (sum of squares; sqrt at finalize)
        float pw = noobj ? 0.0f : fmaxf(hwv, 0.0f);
        float ph = noobj ? 0.0f : fmaxf(hhv, 0.0f);
        float dw = tv[2] - pw, dh = tv[3] - ph;
        a_wh += dw * dw + dh * dh;
        // conf losses
        float cc = fminf(fmaxf(hc, 0.0f), 1.0f);
        float co = noobj ? 0.0f : cc;
        float cn = noobj ? cc : 0.0f;
        float dco = conf - co, dcn = conf - cn;
        a_co += dco * dco;
        a_cn += dcn * dcn;
        // class loss
        float clv = 0.0f;
#pragma unroll
        for (int kk = 0; kk < 20; ++kk) {
            float pc = noobj ? 0.0f : pv[10 + kk];
            float d  = tv[5 + kk] - pc;
            clv += d * d;
        }
        a_cl += clv;
        // ---- end compute ----

        if (k + 1 < nt) {
            asm volatile("s_waitcnt vmcnt(8)" ::: "memory");  // tgt regs valid
            __builtin_amdgcn_sched_barrier(0);
            ST_TGT(buf ^ 1);
            __builtin_amdgcn_sched_barrier(0);
        }
        buf ^= 1;
    }

    // one wave64 butterfly reduce per block
#pragma unroll
    for (int off = 32; off > 0; off >>= 1) {
        a_xy += __shfl_down(a_xy, off);
        a_wh += __shfl_down(a_wh, off);
        a_co += __shfl_down(a_co, off);
        a_cn += __shfl_down(a_cn, off);
        a_cl += __shfl_down(a_cl, off);
    }

    unsigned* ticket = reinterpret_cast<unsigned*>(acc + NSLOT * SLOT_STRIDE);
    int last = 0;
    if (l == 0) {
        float* slot = acc + (bid & (NSLOT - 1)) * SLOT_STRIDE;
        atomicAdd(&slot[0], a_xy);   // device-scope by default
        atomicAdd(&slot[1], a_wh);
        atomicAdd(&slot[2], a_co);
        atomicAdd(&slot[3], a_cn);
        atomicAdd(&slot[4], a_cl);
        // release: all slot adds above become visible to whoever acquires
        unsigned t = __hip_atomic_fetch_add(ticket, 1u, __ATOMIC_ACQ_REL,
                                            __HIP_MEMORY_SCOPE_AGENT);
        last = (t == (unsigned)(NBLK - 1));
    }
    last = __shfl(last, 0);

    if (last) {
        // acquire already done via ticket; lanes 0..15 each own one slot
        float s0 = 0.0f, s1 = 0.0f, s2 = 0.0f, s3 = 0.0f, s4 = 0.0f;
        if (l < NSLOT) {
            const float* slot = acc + l * SLOT_STRIDE;
            s0 = __hip_atomic_load(&slot[0], __ATOMIC_RELAXED, __HIP_MEMORY_SCOPE_AGENT);
            s1 = __hip_atomic_load(&slot[1], __ATOMIC_RELAXED, __HIP_MEMORY_SCOPE_AGENT);
            s2 = __hip_atomic_load(&slot[2], __ATOMIC_RELAXED, __HIP_MEMORY_SCOPE_AGENT);
            s3 = __hip_atomic_load(&slot[3], __ATOMIC_RELAXED, __HIP_MEMORY_SCOPE_AGENT);
            s4 = __hip_atomic_load(&slot[4], __ATOMIC_RELAXED, __HIP_MEMORY_SCOPE_AGENT);
        }
#pragma unroll
        for (int off = 8; off > 0; off >>= 1) {
            s0 += __shfl_down(s0, off);
            s1 += __shfl_down(s1, off);
            s2 += __shfl_down(s2, off);
            s3 += __shfl_down(s3, off);
            s4 += __shfl_down(s4, off);
        }
        if (l == 0) {
            float lxy = s0 * INV_N;
            float lwh = sqrtf(s1 + 1e-6f) * INV_N;
            float lco = s2 * INV_N;
            float lcn = s3 * INV_N;
            float lcl = s4 * INV_N;
            out[0] = lxy;
            out[1] = lwh;
            out[2] = lco;
            out[3] = lcn;
            out[4] = lcl;
            out[5] = 5.0f * lxy + 5.0f * lwh + lco + 0.5f * lcn + lcl;
        }
    }
#undef LD_TGT
#undef DMA_PRED
#undef ST_TGT
}

extern "C" void kernel_launch(void* const* d_in, const int* in_sizes, int n_in,
                              void* d_out, int out_size, void* d_ws, size_t ws_size,
                              hipStream_t stream)
{
    const float* pred = (const float*)d_in[0];
    const float* tgt  = (const float*)d_in[1];
    float* out = (float*)d_out;
    float* acc = (float*)d_ws;   // NSLOT*SLOT_STRIDE floats + 1 uint ticket

    hipMemsetAsync(acc, 0, (NSLOT * SLOT_STRIDE) * sizeof(float) + sizeof(unsigned),
                   stream);
    yolo_partial<<<NBLK, 64, 0, stream>>>(pred, tgt, acc, out);
}

// Round 9
// 33.970 us; speedup vs baseline: 1.8776x; 1.8776x over previous
//
#include <hip/hip_runtime.h>
#include <math.h>

// YOLO loss on MI355X. prediction (N,7,7,30) f32, target (N,7,7,25) f32.
// R8 = exact revert to R6 (best known: 34.06 us).
// Double-buffered LDS pipeline with DUAL staging paths per tile:
//   pred (7680 B) via global_load_lds DMA (8 ops), tgt (6400 B) via plain
//   float4 loads -> 7 VGPR float4 -> ds_write after compute. Splits traffic
//   across the DMA-completion path and the normal VMEM-return path.
// vmcnt choreography per iter: issue tgt-loads(k+1) then pred-DMA(k+1);
//   vmcnt(15) -> pred(k) landed (compute); vmcnt(8) -> tgt loads retired
//   (safe to ds_write); DMAs ride across the iteration boundary.
// No memset / no atomics: per-block dedicated 32 B rows, final kernel reduces.
// (R7's fused-atomic finalize regressed 2x: lockstep persistent grid => all
//  epilogues burst into 16 contended slots + one ticket line. Keep stores.)
constexpr int TOT    = 16384 * 7 * 7;        // 802816 cells
constexpr int TILE   = 64;                   // cells per tile
constexpr int NTILES = TOT / TILE;           // 12544
constexpr int NBLK   = 1280;                 // 5 blocks/CU x 256 CU, resident
constexpr float INV_N = 1.0f / 16384.0f;
constexpr float INV7  = 1.0f / 7.0f;

constexpr int PRED_TILE_B = TILE * 30 * 4;   // 7680 B (480 float4)
constexpr int TGT_TILE_B  = TILE * 25 * 4;   // 6400 B (400 float4)
constexpr int BUF_B       = 14336;           // per-tile LDS buffer

__device__ __forceinline__ float fast_rcp(float x) {
    return __builtin_amdgcn_rcpf(x);         // v_rcp_f32, ~1ulp
}

// DMA 16 B per active lane: global (per-lane addr) -> LDS (wave base + lane*16)
__device__ __forceinline__ void dma16(const void* g, void* lds) {
    __builtin_amdgcn_global_load_lds(
        (const __attribute__((address_space(1))) void*)g,
        (__attribute__((address_space(3))) void*)lds, 16, 0, 0);
}

__global__ __launch_bounds__(64) void yolo_partial(
    const float* __restrict__ pred, const float* __restrict__ tgt,
    float* __restrict__ part /* NBLK rows x 8 floats, fully overwritten */)
{
    __shared__ float4 smem4[2 * BUF_B / 16];     // 28672 B
    char* smem = (char*)smem4;

    const int l   = threadIdx.x;                 // 0..63, one wave
    const int bid = blockIdx.x;

    float a_xy = 0.0f, a_wh = 0.0f, a_co = 0.0f, a_cn = 0.0f, a_cl = 0.0f;

    const int nt = (NTILES - bid + NBLK - 1) / NBLK;   // 9 or 10 tiles

    float4 tr0, tr1, tr2, tr3, tr4, tr5, tr6;    // tgt staging regs (28 VGPR)

#define LD_TGT(tile_)                                                       \
    {                                                                       \
        const float4* gt4 = reinterpret_cast<const float4*>(               \
            tgt + (long)(tile_) * (TILE * 25));                             \
        tr0 = gt4[l];        tr1 = gt4[l + 64];  tr2 = gt4[l + 128];        \
        tr3 = gt4[l + 192];  tr4 = gt4[l + 256]; tr5 = gt4[l + 320];        \
        if (l < 16) tr6 = gt4[l + 384];                                     \
    }  /* 7 vmcnt ops */

#define DMA_PRED(tile_, b)                                                  \
    {                                                                       \
        const char* gp = (const char*)pred + (long)(tile_) * PRED_TILE_B;   \
        char* lb = smem + (b) * BUF_B;                                      \
        _Pragma("unroll")                                                   \
        for (int i = 0; i < 7; ++i)                                         \
            dma16(gp + (size_t)(l + i * 64) * 16, lb + i * 1024);           \
        if (l < 32) dma16(gp + (size_t)(l + 448) * 16, lb + 7168);          \
    }  /* 8 vmcnt ops */

#define ST_TGT(b)                                                           \
    {                                                                       \
        float4* st4 = reinterpret_cast<float4*>(smem + (b) * BUF_B + 7680); \
        st4[l]       = tr0;  st4[l + 64]  = tr1;  st4[l + 128] = tr2;       \
        st4[l + 192] = tr3;  st4[l + 256] = tr4;  st4[l + 320] = tr5;       \
        if (l < 16) st4[l + 384] = tr6;                                     \
    }

    // prologue: stage tile 0 into buf 0
    LD_TGT(bid);
    DMA_PRED(bid, 0);
    asm volatile("s_waitcnt vmcnt(8)" ::: "memory");   // tgt loads retired
    __builtin_amdgcn_sched_barrier(0);
    ST_TGT(0);
    int buf = 0;

    for (int k = 0; k < nt; ++k) {
        const int tile = bid + k * NBLK;
        if (k + 1 < nt) {
            LD_TGT(bid + (k + 1) * NBLK);             // 7 loads
            DMA_PRED(bid + (k + 1) * NBLK, buf ^ 1);  // 8 DMA
            asm volatile("s_waitcnt vmcnt(15)" ::: "memory");  // pred(k) landed
        } else {
            asm volatile("s_waitcnt vmcnt(0)" ::: "memory");
        }
        __builtin_amdgcn_sched_barrier(0);

        // ---- compute tile k from LDS buf ----
        const float* pred_s = (const float*)(smem + buf * BUF_B);
        const float* tgt_s  = pred_s + TILE * 30;

        const int   cell = tile * TILE + l;
        const int   col  = cell % 7;
        const int   row  = (cell / 7) % 7;
        const float fcol = (float)col, frow = (float)row;

        float pv[30];
        {
            const float2* p2 = reinterpret_cast<const float2*>(pred_s + l * 30);
#pragma unroll
            for (int i = 0; i < 15; ++i) {
                float2 v = p2[i];
                pv[2 * i] = v.x; pv[2 * i + 1] = v.y;
            }
        }
        float tv[25];
        {
            const float* tp = tgt_s + l * 25;   // stride 25: conflict-free b32
#pragma unroll
            for (int kk = 0; kk < 25; ++kk) tv[kk] = tp[kk];
        }

        const float conf  = tv[4];
        const bool  noobj = (conf == 0.0f);

        // target abs corners, scaled by conf (reference: _rel2abs(target)*conf)
        float xc = (tv[0] + fcol) * INV7, yc = (tv[1] + frow) * INV7;
        float hw = tv[2] * 0.5f,          hh = tv[3] * 0.5f;
        float tx1 = (xc - hw) * conf, ty1 = (yc - hh) * conf;
        float tx2 = (xc + hw) * conf, ty2 = (yc + hh) * conf;
        float t_area = (tx2 - tx1) * (ty2 - ty1);

        // pred box 1
        float xc1 = (pv[0] + fcol) * INV7, yc1 = (pv[1] + frow) * INV7;
        float hw1 = pv[2] * 0.5f,          hh1 = pv[3] * 0.5f;
        float bx1 = xc1 - hw1, by1 = yc1 - hh1, bx2 = xc1 + hw1, by2 = yc1 + hh1;
        float xi1 = fmaxf(tx1, bx1), yi1 = fmaxf(ty1, by1);
        float xi2 = fminf(tx2, bx2), yi2 = fminf(ty2, by2);
        float inter1 = fmaxf(xi2 - xi1, 0.0f) * fmaxf(yi2 - yi1, 0.0f);
        float area1  = (bx2 - bx1) * (by2 - by1);
        float iou1 = inter1 * fast_rcp(t_area + area1 - inter1 + 1e-6f);

        // pred box 2
        float xc2 = (pv[5] + fcol) * INV7, yc2 = (pv[6] + frow) * INV7;
        float hw2 = pv[7] * 0.5f,          hh2 = pv[8] * 0.5f;
        float cx1 = xc2 - hw2, cy1 = yc2 - hh2, cx2 = xc2 + hw2, cy2 = yc2 + hh2;
        float xj1 = fmaxf(tx1, cx1), yj1 = fmaxf(ty1, cy1);
        float xj2 = fminf(tx2, cx2), yj2 = fminf(ty2, cy2);
        float inter2 = fmaxf(xj2 - xj1, 0.0f) * fmaxf(yj2 - yj1, 0.0f);
        float area2  = (cx2 - cx1) * (cy2 - cy1);
        float iou2 = inter2 * fast_rcp(t_area + area2 - inter2 + 1e-6f);

        // NB: reference as written picks box2 when iou1 > iou2
        const bool pick2 = iou1 > iou2;
        float hx  = pick2 ? pv[5] : pv[0];
        float hy  = pick2 ? pv[6] : pv[1];
        float hwv = pick2 ? pv[7] : pv[2];
        float hhv = pick2 ? pv[8] : pv[3];
        float hc  = pick2 ? pv[9] : pv[4];

        // loss_xy
        float px = noobj ? 0.0f : fmaxf(hx, 0.0f);
        float py = noobj ? 0.0f : fmaxf(hy, 0.0f);
        float dx = tv[0] - px, dy = tv[1] - py;
        a_xy += dx * dx + dy * dy;
        // loss_wh (sum of squares; sqrt in finalize)
        float pw = noobj ? 0.0f : fmaxf(hwv, 0.0f);
        float ph = noobj ? 0.0f : fmaxf(hhv, 0.0f);
        float dw = tv[2] - pw, dh = tv[3] - ph;
        a_wh += dw * dw + dh * dh;
        // conf losses
        float cc = fminf(fmaxf(hc, 0.0f), 1.0f);
        float co = noobj ? 0.0f : cc;
        float cn = noobj ? cc : 0.0f;
        float dco = conf - co, dcn = conf - cn;
        a_co += dco * dco;
        a_cn += dcn * dcn;
        // class loss
        float clv = 0.0f;
#pragma unroll
        for (int kk = 0; kk < 20; ++kk) {
            float pc = noobj ? 0.0f : pv[10 + kk];
            float d  = tv[5 + kk] - pc;
            clv += d * d;
        }
        a_cl += clv;
        // ---- end compute ----

        if (k + 1 < nt) {
            asm volatile("s_waitcnt vmcnt(8)" ::: "memory");  // tgt regs valid
            __builtin_amdgcn_sched_barrier(0);
            ST_TGT(buf ^ 1);
            __builtin_amdgcn_sched_barrier(0);
        }
        buf ^= 1;
    }

    // one wave64 butterfly reduce per block
#pragma unroll
    for (int off = 32; off > 0; off >>= 1) {
        a_xy += __shfl_down(a_xy, off);
        a_wh += __shfl_down(a_wh, off);
        a_co += __shfl_down(a_co, off);
        a_cn += __shfl_down(a_cn, off);
        a_cl += __shfl_down(a_cl, off);
    }
    if (l == 0) {
        float4* r = reinterpret_cast<float4*>(part + bid * 8);
        r[0] = make_float4(a_xy, a_wh, a_co, a_cn);
        r[1] = make_float4(a_cl, 0.0f, 0.0f, 0.0f);
    }
#undef LD_TGT
#undef DMA_PRED
#undef ST_TGT
}

__global__ __launch_bounds__(256) void yolo_final(
    const float* __restrict__ part, float* __restrict__ out)
{
    const int t = threadIdx.x;               // 0..255
    float s0 = 0.0f, s1 = 0.0f, s2 = 0.0f, s3 = 0.0f, s4 = 0.0f;
#pragma unroll
    for (int i = 0; i < NBLK / 256; ++i) {   // 5 rows per thread
        const float4* r = reinterpret_cast<const float4*>(part + (t + i * 256) * 8);
        float4 v0 = r[0], v1 = r[1];
        s0 += v0.x; s1 += v0.y; s2 += v0.z; s3 += v0.w; s4 += v1.x;
    }
#pragma unroll
    for (int off = 32; off > 0; off >>= 1) {
        s0 += __shfl_down(s0, off);
        s1 += __shfl_down(s1, off);
        s2 += __shfl_down(s2, off);
        s3 += __shfl_down(s3, off);
        s4 += __shfl_down(s4, off);
    }
    __shared__ float red[4][5];
    const int lane = t & 63, wid = t >> 6;
    if (lane == 0) {
        red[wid][0] = s0; red[wid][1] = s1; red[wid][2] = s2;
        red[wid][3] = s3; red[wid][4] = s4;
    }
    __syncthreads();
    if (t == 0) {
        float r0 = red[0][0] + red[1][0] + red[2][0] + red[3][0];
        float r1 = red[0][1] + red[1][1] + red[2][1] + red[3][1];
        float r2 = red[0][2] + red[1][2] + red[2][2] + red[3][2];
        float r3 = red[0][3] + red[1][3] + red[2][3] + red[3][3];
        float r4 = red[0][4] + red[1][4] + red[2][4] + red[3][4];
        float lxy = r0 * INV_N;
        float lwh = sqrtf(r1 + 1e-6f) * INV_N;
        float lco = r2 * INV_N;
        float lcn = r3 * INV_N;
        float lcl = r4 * INV_N;
        out[0] = lxy;
        out[1] = lwh;
        out[2] = lco;
        out[3] = lcn;
        out[4] = lcl;
        out[5] = 5.0f * lxy + 5.0f * lwh + lco + 0.5f * lcn + lcl;
    }
}

extern "C" void kernel_launch(void* const* d_in, const int* in_sizes, int n_in,
                              void* d_out, int out_size, void* d_ws, size_t ws_size,
                              hipStream_t stream)
{
    const float* pred = (const float*)d_in[0];
    const float* tgt  = (const float*)d_in[1];
    float* out  = (float*)d_out;
    float* part = (float*)d_ws;              // NBLK*8 floats = 40 KB

    yolo_partial<<<NBLK, 64, 0, stream>>>(pred, tgt, part);
    yolo_final<<<1, 256, 0, stream>>>(part, out);
}